// Round 6
// baseline (666.475 us; speedup 1.0000x reference)
//
#include <hip/hip_runtime.h>

#define NQ 22
#define DIMN (1u << NQ)

// ---------------- compile-time circuit algebra (circuit is fixed) ----------------
struct MaskSet {
    unsigned L[NQ];      // CNOT-ring layer over GF(2): bit b of Lx = parity(x & L[b])
    unsigned Linv[NQ];
    unsigned xm[NQ];     // conjugated X masks
    unsigned zm[NQ];     // conjugated Z masks (suffix masks)
    unsigned frowHi[5];  // P-toggle masks for y bits 17..21 (columns of Linv)
};

constexpr MaskSet buildMasks() {
    MaskSet M{};
    for (int b = 0; b < NQ; ++b) M.L[b] = 1u << b;
    for (int q = 0; q < NQ; ++q) {
        int bc = NQ - 1 - q, bt = NQ - 1 - ((q + 1) % NQ);
        M.L[bt] ^= M.L[bc];
    }
    unsigned mat[NQ] = {}, aug[NQ] = {};
    for (int b = 0; b < NQ; ++b) { mat[b] = M.L[b]; aug[b] = 1u << b; }
    for (int col = 0; col < NQ; ++col) {
        int piv = col;
        while (!((mat[piv] >> col) & 1u)) ++piv;
        unsigned tm = mat[piv]; mat[piv] = mat[col]; mat[col] = tm;
        unsigned ta = aug[piv]; aug[piv] = aug[col]; aug[col] = ta;
        for (int r = 0; r < NQ; ++r)
            if (r != col && ((mat[r] >> col) & 1u)) { mat[r] ^= mat[col]; aug[r] ^= aug[col]; }
    }
    for (int b = 0; b < NQ; ++b) M.Linv[b] = aug[b];
    for (int j = 0; j < NQ; ++j) {
        int b = NQ - 1 - j;
        unsigned xmv = 0;
        for (int r = 0; r < NQ; ++r)
            if ((aug[r] >> b) & 1u) xmv |= 1u << r;
        M.xm[j] = xmv;       // q0..9: {21-j,20-j}; q10..20: low pairs; q21: {0,20,21}
        M.zm[j] = M.L[b];    // suffix masks
    }
    for (int j = 0; j < 5; ++j) {
        unsigned f = 0;
        for (int r = 0; r < NQ; ++r)
            if ((aug[r] >> (17 + j)) & 1u) f |= 1u << r;
        M.frowHi[j] = f;
    }
    return M;
}
constexpr int topbit_c(unsigned v) { int b = 0; while (v >> (b + 1)) ++b; return b; }

__device__ __forceinline__ float wave_sum(float v) {
    v += __shfl_down(v, 32); v += __shfl_down(v, 16); v += __shfl_down(v, 8);
    v += __shfl_down(v, 4);  v += __shfl_down(v, 2);  v += __shfl_down(v, 1);
    return v;
}
__device__ __forceinline__ float fflip(float v, unsigned sbit31) {
    return __int_as_float(__float_as_int(v) ^ (int)sbit31);
}
__device__ __forceinline__ unsigned ph4(unsigned g) { return g ^ ((g >> 6) & 3u); }

// ---------------- prep: zero accumulators, compute cos/sin tables ----------------
__global__ __launch_bounds__(256) void k_prep(const float* __restrict__ theta,
                                              float* __restrict__ acc,
                                              float* __restrict__ trig) {
    int t = threadIdx.x;
    acc[t] = 0.f;
    if (t < 2 * NQ) {
        int l = t / NQ, q = t % NQ, b = NQ - 1 - q;
        float h = 0.5f * theta[t];
        trig[l * 2 * NQ + b]      = cosf(h);
        trig[l * 2 * NQ + NQ + b] = sinf(h);
    }
}

// ---- generator in e=bits17..21 tile + gates 17..21 + measure q1,q2,q3 ----
__global__ __launch_bounds__(256) void k_genHi(float* __restrict__ phi,
                                               const float* __restrict__ trig,
                                               float* __restrict__ acc) {
    constexpr MaskSet M = buildMasks();
    unsigned base = blockIdx.x * 256u + threadIdx.x;       // y bits 0..16
    float cv[NQ], sv[NQ];
#pragma unroll
    for (int b = 0; b < NQ; ++b) { cv[b] = trig[b]; sv[b] = trig[NQ + b]; }
    unsigned P0 = 0;
#pragma unroll
    for (int b = 0; b < NQ; ++b)
        P0 |= ((unsigned)__popc(base & M.Linv[b]) & 1u) << b;
    float c2[5], s2[5];
#pragma unroll
    for (int j = 0; j < 5; ++j) {
        c2[j] = trig[2 * NQ + 17 + j];
        s2[j] = trig[3 * NQ + 17 + j];
    }
    float v0[32], v1[32];
#pragma unroll
    for (int e = 0; e < 32; ++e) {
        unsigned F = 0;
        if (e & 1)  F ^= M.frowHi[0];
        if (e & 2)  F ^= M.frowHi[1];
        if (e & 4)  F ^= M.frowHi[2];
        if (e & 8)  F ^= M.frowHi[3];
        if (e & 16) F ^= M.frowHi[4];
        unsigned P = P0 ^ F;
        float prod = 1.f;
#pragma unroll
        for (int b = 1; b < NQ; ++b)
            prod *= ((P >> b) & 1u) ? sv[b] : cv[b];
        v0[e] = prod * ((P & 1u) ? sv[0] : cv[0]);
        v1[e] = prod * ((P & 1u) ? cv[0] : -sv[0]);
    }
#pragma unroll
    for (int j = 0; j < 5; ++j) {
#pragma unroll
        for (int e = 0; e < 32; ++e) {
            if (!(e & (1 << j))) {
                int e1 = e | (1 << j);
                float a0 = v0[e], a1 = v0[e1];
                v0[e]  = c2[j] * a0 - s2[j] * a1;
                v0[e1] = s2[j] * a0 + c2[j] * a1;
                float b0 = v1[e], b1 = v1[e1];
                v1[e]  = c2[j] * b0 - s2[j] * b1;
                v1[e1] = s2[j] * b0 + c2[j] * b1;
            }
        }
    }
#pragma unroll
    for (int e = 0; e < 32; ++e) {
        unsigned a = base | ((unsigned)e << 17);
        phi[a] = v0[e];
        phi[DIMN + a] = v1[e];
    }
    // measure q1..q3 (x-pairs and z-masks entirely within bits 17..21)
    int lane = threadIdx.x & 63;
#pragma unroll
    for (int i = 1; i <= 3; ++i) {
        unsigned ex  = M.xm[i] >> 17;
        unsigned zme = M.zm[i] >> 17;
        float t00 = 0.f, t11 = 0.f, t01 = 0.f, u01 = 0.f;
#pragma unroll
        for (int e = 0; e < 32; ++e) {
            int ep = e ^ (int)ex;
            t00 += v0[e] * v0[ep];
            t11 += v1[e] * v1[ep];
            float p = v0[e] * v1[ep];
            t01 += p;
            unsigned sg = ((unsigned)__popc((unsigned)ep & zme) & 1u) << 31;
            u01 += fflip(p, sg);
        }
        float vals[4] = { t00, t11, t01, u01 };
#pragma unroll
        for (int j = 0; j < 4; ++j) {
            float v = wave_sum(vals[j]);
            if (lane == 0) atomicAdd(&acc[4 * i + j], v);
        }
    }
}

// ---- e=bits12..17 tile: gates 12..16 + measure q4..q8 (no LDS, no barriers) ----
__global__ __launch_bounds__(256) void k_mid(float* __restrict__ phi,
                                             const float* __restrict__ trig,
                                             float* __restrict__ acc) {
    constexpr MaskSet M = buildMasks();
    unsigned tid = blockIdx.x * 256u + threadIdx.x;        // [0, 2^16)
    unsigned base = (tid & 0xFFFu) | ((tid >> 12) << 18);  // bits 0..11 + 18..21
    float v0[64], v1[64];
#pragma unroll
    for (int e = 0; e < 64; ++e) {
        unsigned a = base | ((unsigned)e << 12);
        v0[e] = phi[a];
        v1[e] = phi[DIMN + a];
    }
    float c[5], s[5];
#pragma unroll
    for (int j = 0; j < 5; ++j) {
        c[j] = trig[2 * NQ + 12 + j];
        s[j] = trig[3 * NQ + 12 + j];
    }
#pragma unroll
    for (int j = 0; j < 5; ++j) {
#pragma unroll
        for (int e = 0; e < 64; ++e) {
            if (!(e & (1 << j))) {
                int e1 = e | (1 << j);
                float a0 = v0[e], a1 = v0[e1];
                v0[e]  = c[j] * a0 - s[j] * a1;
                v0[e1] = s[j] * a0 + c[j] * a1;
                float b0 = v1[e], b1 = v1[e1];
                v1[e]  = c[j] * b0 - s[j] * b1;
                v1[e1] = s[j] * b0 + c[j] * b1;
            }
        }
    }
#pragma unroll
    for (int e = 0; e < 64; ++e) {
        unsigned a = base | ((unsigned)e << 12);
        phi[a] = v0[e];
        phi[DIMN + a] = v1[e];
    }
    // measure q4..q8 (x-pairs within bits 12..17; z-masks in bits >=13)
    int lane = threadIdx.x & 63;
#pragma unroll
    for (int i = 4; i <= 8; ++i) {
        unsigned ex  = M.xm[i] >> 12;                      // 6-bit
        unsigned zme = (M.zm[i] >> 12) & 63u;
        unsigned bs31 = ((unsigned)__popc(base & M.zm[i]) & 1u) << 31;
        float t00 = 0.f, t11 = 0.f, t01 = 0.f, u01 = 0.f;
#pragma unroll
        for (int e = 0; e < 64; ++e) {
            int ep = e ^ (int)ex;
            t00 += v0[e] * v0[ep];
            t11 += v1[e] * v1[ep];
            float p = v0[e] * v1[ep];
            t01 += p;
            unsigned sg = ((unsigned)__popc((unsigned)ep & zme) & 1u) << 31;
            u01 += fflip(p, sg ^ bs31);
        }
        float vals[4] = { t00, t11, t01, u01 };
#pragma unroll
        for (int j = 0; j < 4; ++j) {
            float v = wave_sum(vals[j]);
            if (lane == 0) atomicAdd(&acc[4 * i + j], v);
        }
    }
}

// ---- RY layer 2 bits 0..11 (register-staged) + q10..q20 X/Y + ALL Z measurements ----
__global__ __launch_bounds__(256) void k_low(float* __restrict__ phi,
                                             const float* __restrict__ trig,
                                             float* __restrict__ acc) {
    constexpr MaskSet M = buildMasks();
    __shared__ float As[4096];
    __shared__ float Bs[4096];
    __shared__ float red[4 * 44];
    float4* As4 = (float4*)As;
    float4* Bs4 = (float4*)Bs;
    int t = threadIdx.x;
    unsigned base = blockIdx.x * 4096u;
    float a[16], b[16];

    // ---- phase 0: global load (16 consecutive elems/thread), gates bits 0..3 ----
    {
        const float4* g0 = (const float4*)(phi + base);
        const float4* g1 = (const float4*)(phi + DIMN + base);
#pragma unroll
        for (int k = 0; k < 4; ++k) {
            float4 va = g0[4 * t + k];
            a[4 * k] = va.x; a[4 * k + 1] = va.y; a[4 * k + 2] = va.z; a[4 * k + 3] = va.w;
            float4 vb = g1[4 * t + k];
            b[4 * k] = vb.x; b[4 * k + 1] = vb.y; b[4 * k + 2] = vb.z; b[4 * k + 3] = vb.w;
        }
#pragma unroll
        for (int g = 0; g < 4; ++g) {
            float c = trig[2 * NQ + g], s = trig[3 * NQ + g];
#pragma unroll
            for (int e = 0; e < 16; ++e) {
                if (!(e & (1 << g))) {
                    int e1 = e | (1 << g);
                    float x0 = a[e], x1 = a[e1];
                    a[e] = c * x0 - s * x1; a[e1] = s * x0 + c * x1;
                    float y0 = b[e], y1 = b[e1];
                    b[e] = c * y0 - s * y1; b[e1] = s * y0 + c * y1;
                }
            }
        }
        unsigned sw = (unsigned)(t >> 4) & 3u;
#pragma unroll
        for (int k = 0; k < 4; ++k) {
            unsigned f = ((unsigned)(4 * t + k)) ^ sw;
            As4[f] = make_float4(a[4 * k], a[4 * k + 1], a[4 * k + 2], a[4 * k + 3]);
            Bs4[f] = make_float4(b[4 * k], b[4 * k + 1], b[4 * k + 2], b[4 * k + 3]);
        }
    }
    __syncthreads();

    // ---- phase 1: exchange to bits 4..7 ownership, gates bits 4..7 ----
    {
        unsigned lo = (unsigned)t & 15u, hi = (unsigned)t >> 4;
        unsigned swz = (hi & 3u) << 2;
#pragma unroll
        for (int j = 0; j < 16; ++j) {
            unsigned i = lo | ((unsigned)j << 4) | (hi << 8);
            a[j] = As[i ^ swz];
            b[j] = Bs[i ^ swz];
        }
#pragma unroll
        for (int g = 0; g < 4; ++g) {
            float c = trig[2 * NQ + 4 + g], s = trig[3 * NQ + 4 + g];
#pragma unroll
            for (int e = 0; e < 16; ++e) {
                if (!(e & (1 << g))) {
                    int e1 = e | (1 << g);
                    float x0 = a[e], x1 = a[e1];
                    a[e] = c * x0 - s * x1; a[e1] = s * x0 + c * x1;
                    float y0 = b[e], y1 = b[e1];
                    b[e] = c * y0 - s * y1; b[e1] = s * y0 + c * y1;
                }
            }
        }
#pragma unroll
        for (int j = 0; j < 16; ++j) {
            unsigned i = lo | ((unsigned)j << 4) | (hi << 8);
            As[i ^ swz] = a[j];
            Bs[i ^ swz] = b[j];
        }
    }
    __syncthreads();

    // ---- phase 2: exchange to bits 8..11 ownership, gates bits 8..11, write out ----
    {
#pragma unroll
        for (int j = 0; j < 16; ++j) {
            unsigned i = (unsigned)t | ((unsigned)j << 8);
            unsigned p = i ^ (((unsigned)j & 3u) << 2);
            a[j] = As[p];
            b[j] = Bs[p];
        }
#pragma unroll
        for (int g = 0; g < 4; ++g) {
            float c = trig[2 * NQ + 8 + g], s = trig[3 * NQ + 8 + g];
#pragma unroll
            for (int e = 0; e < 16; ++e) {
                if (!(e & (1 << g))) {
                    int e1 = e | (1 << g);
                    float x0 = a[e], x1 = a[e1];
                    a[e] = c * x0 - s * x1; a[e1] = s * x0 + c * x1;
                    float y0 = b[e], y1 = b[e1];
                    b[e] = c * y0 - s * y1; b[e1] = s * y0 + c * y1;
                }
            }
        }
#pragma unroll
        for (int j = 0; j < 16; ++j) {
            unsigned i = (unsigned)t | ((unsigned)j << 8);
            phi[base + i] = a[j];
            phi[DIMN + base + i] = b[j];
            unsigned p = i ^ (((unsigned)j & 3u) << 2);
            As[p] = a[j];
            Bs[p] = b[j];
        }
    }

    // ---- fused Z measurement from final registers a[],b[] ----
    float SSv[3], z0v[3], z1v[3], z2v[3], d4v[3];
    {
#pragma unroll
        for (int c = 0; c < 3; ++c) {
            float p[16];
#pragma unroll
            for (int j = 0; j < 16; ++j)
                p[j] = (c == 0) ? a[j] * a[j] : (c == 1) ? b[j] * b[j] : a[j] * b[j];
            float s1[8], d1[8];
#pragma unroll
            for (int j = 0; j < 8; ++j) { s1[j] = p[j] + p[j + 8]; d1[j] = p[j] - p[j + 8]; }
            float s2[4], d2[4];
#pragma unroll
            for (int j = 0; j < 4; ++j) { s2[j] = s1[j] + s1[j + 4]; d2[j] = d1[j] - d1[j + 4]; }
            float d3a = d2[0] - d2[2], d3b = d2[1] - d2[3];
            SSv[c] = (s2[0] + s2[1]) + (s2[2] + s2[3]);
            z0v[c] = ((d1[0] + d1[1]) + (d1[2] + d1[3])) + ((d1[4] + d1[5]) + (d1[6] + d1[7]));
            z1v[c] = (d2[0] + d2[1]) + (d2[2] + d2[3]);
            z2v[c] = d3a + d3b;
            d4v[c] = d3a - d3b;
        }
    }
    {
        unsigned Wt = (unsigned)t;
        Wt ^= Wt >> 1; Wt ^= Wt >> 2; Wt ^= Wt >> 4;
        int lane = t & 63, w = t >> 6;
#pragma unroll
        for (int c = 0; c < 3; ++c) {
            float v;
            v = wave_sum(SSv[c]); if (lane == 0) red[w * 39 + c] = v;
            v = wave_sum(z0v[c]); if (lane == 0) red[w * 39 + 3 + c] = v;
            v = wave_sum(z1v[c]); if (lane == 0) red[w * 39 + 6 + c] = v;
            v = wave_sum(z2v[c]); if (lane == 0) red[w * 39 + 9 + c] = v;
            v = wave_sum(d4v[c]); if (lane == 0) red[w * 39 + 12 + c] = v;
#pragma unroll
            for (int k = 4; k < 12; ++k) {
                unsigned sb = ((Wt >> (11 - k)) & 1u) << 31;
                v = wave_sum(fflip(d4v[c], sb));
                if (lane == 0) red[w * 39 + 3 + 3 * k + c] = v;
            }
        }
    }
    __syncthreads();
    if (t < 66) {
        int c = t % 3, q = t / 3;
        int slot = (q == 0 || q == 21) ? (3 + 33 + c) : (q < 10 ? c : 3 + 3 * (q - 10) + c);
        float val = red[slot] + red[39 + slot] + red[78 + slot] + red[117 + slot];
        unsigned sg = (unsigned)__popc(base & M.zm[q]) & 1u;
        atomicAdd(&acc[4 * NQ + 3 * q + c], sg ? -val : val);
    }
    __syncthreads();

    // ---- measurements q10..q20 (masks within bits 0..11), vectorized from LDS ----
    int lane = t & 63, w = t >> 6;
#pragma unroll
    for (int i = 0; i < 11; ++i) {
        unsigned m = M.xm[10 + i], zm = M.zm[10 + i];
        unsigned zb = (unsigned)__popc(base & zm) & 1u;
        float t00 = 0.f, t11 = 0.f, t01 = 0.f, u01 = 0.f;
        if (i < 10) {
            int gb = topbit_c(M.xm[10 + i]) - 2;
            unsigned mg4 = m >> 2;
            unsigned swap2 = m & 3u;            // 0 or 2
#pragma unroll
            for (int r = 0; r < 2; ++r) {
                unsigned gc = (unsigned)t + 256u * r;
                unsigned g = ((gc >> gb) << (gb + 1)) | (gc & ((1u << gb) - 1u));
                unsigned gx = g ^ mg4;
                float4 a0 = As4[ph4(g)],  a1 = Bs4[ph4(g)];
                float4 b0 = As4[ph4(gx)], b1 = Bs4[ph4(gx)];
                if (swap2) {
                    b0 = make_float4(b0.z, b0.w, b0.x, b0.y);
                    b1 = make_float4(b1.z, b1.w, b1.x, b1.y);
                }
                unsigned szg = ((unsigned)__popc((g << 2) & zm) + zb) & 1u;
                unsigned szx = ((unsigned)__popc((gx << 2) & zm) + zb) & 1u;
                unsigned fg = szg << 31, fx = szx << 31;
                const float* A0 = &a0.x; const float* A1 = &a1.x;
                const float* B0 = &b0.x; const float* B1 = &b1.x;
#pragma unroll
                for (int j = 0; j < 4; ++j) {
                    t00 += A0[j] * B0[j];
                    t11 += A1[j] * B1[j];
                    float p = A0[j] * B1[j], r2 = B0[j] * A1[j];
                    t01 += p + r2;
                    u01 += fflip(p, fx) + fflip(r2, fg);
                }
            }
            t00 *= 2.f; t11 *= 2.f;
        } else {
            // q20: m = 3, partner within float4
#pragma unroll
            for (int k = 0; k < 4; ++k) {
                unsigned g = (unsigned)t + 256u * k;
                float4 a0 = As4[ph4(g)], a1 = Bs4[ph4(g)];
                unsigned szg = ((unsigned)__popc((g << 2) & zm) + zb) & 1u;
                const float* A0 = &a0.x; const float* A1 = &a1.x;
#pragma unroll
                for (int j = 0; j < 4; ++j) {
                    int jx = j ^ 3;
                    float p = A0[j] * A0[jx];
                    float q2 = A1[j] * A1[jx];
                    float cr = A0[j] * A1[jx];
                    t00 += p; t11 += q2; t01 += cr;
                    unsigned sj = ((unsigned)(jx >> 1) & 1u) ^ szg;   // zm&3 == 2
                    u01 += fflip(cr, sj << 31);
                }
            }
        }
        float vals[4] = { t00, t11, t01, u01 };
#pragma unroll
        for (int j = 0; j < 4; ++j) {
            float v = wave_sum(vals[j]);
            if (lane == 0) red[w * 44 + 4 * i + j] = v;
        }
    }
    __syncthreads();
    if (t < 44) {
        float r = red[t] + red[44 + t] + red[88 + t] + red[132 + t];
        atomicAdd(&acc[40 + t], r);
    }
}

// ------- slice X/Y measurements for q0, q9, q21 — grid (256, 3) -----------
struct Meas3Arg { unsigned xm[3]; unsigned zm[3]; int gbit[3]; int qn[3]; };

__global__ __launch_bounds__(256) void k_measS(const float* __restrict__ phi,
                                               float* __restrict__ acc,
                                               Meas3Arg M) {
    __shared__ float red[16];
    int t = threadIdx.x;
    int slice = blockIdx.y;
    unsigned m = M.xm[slice], zm = M.zm[slice];
    int gb = M.gbit[slice];
    unsigned mg4 = m >> 2;
    unsigned ml2 = m & 3u;                      // 0 or 1
    unsigned zl = zm & 3u;
    unsigned pg31[4], px31[4];
#pragma unroll
    for (int j = 0; j < 4; ++j) {
        pg31[j] = (((unsigned)__popc((unsigned)j & zl) & 1u) << 31);
        px31[j] = (((unsigned)__popc(((unsigned)j ^ ml2) & zl) & 1u) << 31);
    }
    unsigned tid = blockIdx.x * 256u + (unsigned)t;   // [0, 65536)
    const float4* p0 = (const float4*)phi;
    const float4* p1 = (const float4*)(phi + DIMN);
    float t00 = 0.f, t11 = 0.f, t01 = 0.f, u01 = 0.f;
#pragma unroll
    for (int it = 0; it < 8; ++it) {
        unsigned gc = tid + (unsigned)it * 65536u;    // [0, 2^19)
        unsigned g = ((gc >> gb) << (gb + 1)) | (gc & ((1u << gb) - 1u));
        unsigned gx = g ^ mg4;
        float4 a0 = p0[g], a1 = p1[g];
        float4 b0 = p0[gx], b1 = p1[gx];
        if (ml2) {
            b0 = make_float4(b0.y, b0.x, b0.w, b0.z);
            b1 = make_float4(b1.y, b1.x, b1.w, b1.z);
        }
        unsigned fg = (((unsigned)__popc((g << 2) & zm) & 1u) << 31);
        unsigned fx = (((unsigned)__popc((gx << 2) & zm) & 1u) << 31);
        const float* A0 = &a0.x; const float* A1 = &a1.x;
        const float* B0 = &b0.x; const float* B1 = &b1.x;
#pragma unroll
        for (int j = 0; j < 4; ++j) {
            t00 += A0[j] * B0[j];
            t11 += A1[j] * B1[j];
            float p = A0[j] * B1[j], r = B0[j] * A1[j];
            t01 += p + r;
            u01 += fflip(p, fx ^ px31[j]) + fflip(r, fg ^ pg31[j]);
        }
    }
    t00 *= 2.f; t11 *= 2.f;
    int lane = t & 63, w = t >> 6;
    float vals[4] = { t00, t11, t01, u01 };
#pragma unroll
    for (int j = 0; j < 4; ++j) {
        float v = wave_sum(vals[j]);
        if (lane == 0) red[w * 4 + j] = v;
    }
    __syncthreads();
    if (t < 4) {
        float r = red[t] + red[4 + t] + red[8 + t] + red[12 + t];
        atomicAdd(&acc[4 * M.qn[slice] + t], r);
    }
}

// ---------------- finalize: combine 154 sums into the scalar loss ----------------
__global__ __launch_bounds__(64) void k_final(const float* __restrict__ acc,
                                              float* __restrict__ out) {
    int t = threadIdx.x;
    float v = 0.f;
    if (t < NQ) {
        float t00 = acc[4 * t], t11 = acc[4 * t + 1];
        float t01 = acc[4 * t + 2], u01 = acc[4 * t + 3];
        float d = t00 - t11;
        v = 0.5f * d * d + 2.f * t01 * t01 + 2.f * u01 * u01;   // X op + Y op
    } else if (t < 2 * NQ) {
        int q = t - NQ;
        float z0 = acc[4 * NQ + 3 * q], z1 = acc[4 * NQ + 3 * q + 1];
        float zz = acc[4 * NQ + 3 * q + 2];
        float d = z0 - z1;
        v = 0.5f * d * d + 2.f * zz * zz;                       // Z op
    }
    v += __shfl_down(v, 32); v += __shfl_down(v, 16); v += __shfl_down(v, 8);
    v += __shfl_down(v, 4);  v += __shfl_down(v, 2);  v += __shfl_down(v, 1);
    if (t == 0) out[0] = v;
}

extern "C" void kernel_launch(void* const* d_in, const int* in_sizes, int n_in,
                              void* d_out, int out_size, void* d_ws, size_t ws_size,
                              hipStream_t stream) {
    const float* theta = (const float*)d_in[0];
    float* out  = (float*)d_out;
    float* ws   = (float*)d_ws;
    float* phi  = ws;                          // 2 * DIMN floats (32 MB)
    float* acc  = ws + 2 * (size_t)DIMN;       // 256 floats
    float* trig = acc + 256;                   // 88 floats

    constexpr MaskSet M = buildMasks();

    Meas3Arg m3;
    const int qs[3] = { 0, 9, 21 };
    for (int i = 0; i < 3; ++i) {
        int q = qs[i];
        m3.xm[i] = M.xm[q]; m3.zm[i] = M.zm[q];
        m3.gbit[i] = topbit_c(M.xm[q]) - 2;
        m3.qn[i] = q;
    }

    k_prep<<<1, 256, 0, stream>>>(theta, acc, trig);
    k_genHi<<<512, 256, 0, stream>>>(phi, trig, acc);
    k_mid<<<256, 256, 0, stream>>>(phi, trig, acc);
    k_low<<<1024, 256, 0, stream>>>(phi, trig, acc);
    k_measS<<<dim3(256, 3), 256, 0, stream>>>(phi, acc, m3);
    k_final<<<1, 64, 0, stream>>>(acc, out);
}

// Round 7
// 166.475 us; speedup vs baseline: 4.0035x; 4.0035x over previous
//
#include <hip/hip_runtime.h>

#define NQ 22
#define DIMN (1u << NQ)

// ---------------- compile-time circuit algebra (circuit is fixed) ----------------
struct MaskSet {
    unsigned L[NQ];      // CNOT-ring layer over GF(2): bit b of Lx = parity(x & L[b])
    unsigned Linv[NQ];
    unsigned xm[NQ];     // conjugated X masks
    unsigned zm[NQ];     // conjugated Z masks (suffix masks)
    unsigned frowHi[5];  // P-toggle masks for y bits 17..21 (columns of Linv)
};

constexpr MaskSet buildMasks() {
    MaskSet M{};
    for (int b = 0; b < NQ; ++b) M.L[b] = 1u << b;
    for (int q = 0; q < NQ; ++q) {
        int bc = NQ - 1 - q, bt = NQ - 1 - ((q + 1) % NQ);
        M.L[bt] ^= M.L[bc];
    }
    unsigned mat[NQ] = {}, aug[NQ] = {};
    for (int b = 0; b < NQ; ++b) { mat[b] = M.L[b]; aug[b] = 1u << b; }
    for (int col = 0; col < NQ; ++col) {
        int piv = col;
        while (!((mat[piv] >> col) & 1u)) ++piv;
        unsigned tm = mat[piv]; mat[piv] = mat[col]; mat[col] = tm;
        unsigned ta = aug[piv]; aug[piv] = aug[col]; aug[col] = ta;
        for (int r = 0; r < NQ; ++r)
            if (r != col && ((mat[r] >> col) & 1u)) { mat[r] ^= mat[col]; aug[r] ^= aug[col]; }
    }
    for (int b = 0; b < NQ; ++b) M.Linv[b] = aug[b];
    for (int j = 0; j < NQ; ++j) {
        int b = NQ - 1 - j;
        unsigned xmv = 0;
        for (int r = 0; r < NQ; ++r)
            if ((aug[r] >> b) & 1u) xmv |= 1u << r;
        M.xm[j] = xmv;       // q0..9: {21-j,20-j}; q10..20: low pairs; q21: {0,20,21}
        M.zm[j] = M.L[b];    // suffix masks
    }
    for (int j = 0; j < 5; ++j) {
        unsigned f = 0;
        for (int r = 0; r < NQ; ++r)
            if ((aug[r] >> (17 + j)) & 1u) f |= 1u << r;
        M.frowHi[j] = f;
    }
    return M;
}
constexpr int topbit_c(unsigned v) { int b = 0; while (v >> (b + 1)) ++b; return b; }
constexpr unsigned unionHi() {
    MaskSet M = buildMasks();
    unsigned u = 0;
    for (int j = 0; j < 5; ++j) u |= M.frowHi[j];
    return u;
}
static_assert((unionHi() & 0xFFFFu) == 0, "frowHi must only touch bits 16..21");

__device__ __forceinline__ float wave_sum(float v) {
    v += __shfl_down(v, 32); v += __shfl_down(v, 16); v += __shfl_down(v, 8);
    v += __shfl_down(v, 4);  v += __shfl_down(v, 2);  v += __shfl_down(v, 1);
    return v;
}
__device__ __forceinline__ float fflip(float v, unsigned sbit31) {
    return __int_as_float(__float_as_int(v) ^ (int)sbit31);
}
__device__ __forceinline__ unsigned ph4(unsigned g) { return g ^ ((g >> 6) & 3u); }

// ---------------- prep: zero accumulators, compute cos/sin tables ----------------
__global__ __launch_bounds__(256) void k_prep(const float* __restrict__ theta,
                                              float* __restrict__ acc,
                                              float* __restrict__ trig) {
    int t = threadIdx.x;
    acc[t] = 0.f;
    if (t < 2 * NQ) {
        int l = t / NQ, q = t % NQ, b = NQ - 1 - q;
        float h = 0.5f * theta[t];
        trig[l * 2 * NQ + b]      = cosf(h);
        trig[l * 2 * NQ + NQ + b] = sinf(h);
    }
}

// ---- generator in e=bits17..21 tile + gates 17..21 + measure q1,q2,q3 ----
// Product split: common factor over bits 0..15 (Fe never touches them) x 6-bit
// variable part over bits 16..21 -> no cv/sv register arrays, no spill.
__global__ __launch_bounds__(256, 1) void k_genHi(float* __restrict__ phi,
                                                  const float* __restrict__ trig,
                                                  float* __restrict__ acc) {
    constexpr MaskSet M = buildMasks();
    __shared__ float red[4 * 12];
    unsigned base = blockIdx.x * 256u + threadIdx.x;       // y bits 0..16
    unsigned P0 = 0;
#pragma unroll
    for (int b = 0; b < NQ; ++b)
        P0 |= ((unsigned)__popc(base & M.Linv[b]) & 1u) << b;
    // common product over bits 1..15 (consumed immediately, not kept)
    float pc = 1.f;
#pragma unroll
    for (int b = 1; b < 16; ++b) {
        float cvb = trig[b], svb = trig[NQ + b];
        pc *= ((P0 >> b) & 1u) ? svb : cvb;
    }
    float cv0 = trig[0], sv0 = trig[NQ];
    float C0 = pc * ((P0 & 1u) ? sv0 : cv0);
    float C1 = pc * ((P0 & 1u) ? cv0 : -sv0);
    // variable part: bits 16..21
    float cb[6], sb[6];
#pragma unroll
    for (int k = 0; k < 6; ++k) { cb[k] = trig[16 + k]; sb[k] = trig[NQ + 16 + k]; }
    unsigned u0 = P0 >> 16;                                // 6 bits
    float v0[32], v1[32];
#pragma unroll
    for (int e = 0; e < 32; ++e) {
        unsigned F = 0;
        if (e & 1)  F ^= M.frowHi[0];
        if (e & 2)  F ^= M.frowHi[1];
        if (e & 4)  F ^= M.frowHi[2];
        if (e & 8)  F ^= M.frowHi[3];
        if (e & 16) F ^= M.frowHi[4];
        unsigned u = u0 ^ (F >> 16);
        float vp = (u & 1u) ? sb[0] : cb[0];
#pragma unroll
        for (int k = 1; k < 6; ++k) vp *= ((u >> k) & 1u) ? sb[k] : cb[k];
        v0[e] = vp * C0;
        v1[e] = vp * C1;
    }
    float c2[5], s2[5];
#pragma unroll
    for (int j = 0; j < 5; ++j) {
        c2[j] = trig[2 * NQ + 17 + j];
        s2[j] = trig[3 * NQ + 17 + j];
    }
#pragma unroll
    for (int j = 0; j < 5; ++j) {
#pragma unroll
        for (int e = 0; e < 32; ++e) {
            if (!(e & (1 << j))) {
                int e1 = e | (1 << j);
                float a0 = v0[e], a1 = v0[e1];
                v0[e]  = c2[j] * a0 - s2[j] * a1;
                v0[e1] = s2[j] * a0 + c2[j] * a1;
                float b0 = v1[e], b1 = v1[e1];
                v1[e]  = c2[j] * b0 - s2[j] * b1;
                v1[e1] = s2[j] * b0 + c2[j] * b1;
            }
        }
    }
#pragma unroll
    for (int e = 0; e < 32; ++e) {
        unsigned a = base | ((unsigned)e << 17);
        phi[a] = v0[e];
        phi[DIMN + a] = v1[e];
    }
    // measure q1..q3 (x-pairs and z-masks entirely within bits 17..21)
    int lane = threadIdx.x & 63, w = threadIdx.x >> 6;
#pragma unroll
    for (int i = 1; i <= 3; ++i) {
        unsigned ex  = M.xm[i] >> 17;
        unsigned zme = M.zm[i] >> 17;
        float t00 = 0.f, t11 = 0.f, t01 = 0.f, u01 = 0.f;
#pragma unroll
        for (int e = 0; e < 32; ++e) {
            int ep = e ^ (int)ex;
            t00 += v0[e] * v0[ep];
            t11 += v1[e] * v1[ep];
            float p = v0[e] * v1[ep];
            t01 += p;
            unsigned sg = ((unsigned)__popc((unsigned)ep & zme) & 1u) << 31;
            u01 += fflip(p, sg);
        }
        float vals[4] = { t00, t11, t01, u01 };
#pragma unroll
        for (int j = 0; j < 4; ++j) {
            float v = wave_sum(vals[j]);
            if (lane == 0) red[w * 12 + (i - 1) * 4 + j] = v;
        }
    }
    __syncthreads();
    int t = threadIdx.x;
    if (t < 12) {
        float r = red[t] + red[12 + t] + red[24 + t] + red[36 + t];
        atomicAdd(&acc[4 + t], r);                          // acc[4..15] = q1..q3
    }
}

// ---- e=bits12..17 tile: gates 12..16 + measure q4..q8 (no spill, LDS reduce) ----
__global__ __launch_bounds__(256, 1) void k_mid(float* __restrict__ phi,
                                                const float* __restrict__ trig,
                                                float* __restrict__ acc) {
    constexpr MaskSet M = buildMasks();
    __shared__ float red[4 * 20];
    unsigned tid = blockIdx.x * 256u + threadIdx.x;        // [0, 2^16)
    unsigned base = (tid & 0xFFFu) | ((tid >> 12) << 18);  // bits 0..11 + 18..21
    float v0[64], v1[64];
#pragma unroll
    for (int e = 0; e < 64; ++e) {
        unsigned a = base | ((unsigned)e << 12);
        v0[e] = phi[a];
        v1[e] = phi[DIMN + a];
    }
    float c[5], s[5];
#pragma unroll
    for (int j = 0; j < 5; ++j) {
        c[j] = trig[2 * NQ + 12 + j];
        s[j] = trig[3 * NQ + 12 + j];
    }
#pragma unroll
    for (int j = 0; j < 5; ++j) {
#pragma unroll
        for (int e = 0; e < 64; ++e) {
            if (!(e & (1 << j))) {
                int e1 = e | (1 << j);
                float a0 = v0[e], a1 = v0[e1];
                v0[e]  = c[j] * a0 - s[j] * a1;
                v0[e1] = s[j] * a0 + c[j] * a1;
                float b0 = v1[e], b1 = v1[e1];
                v1[e]  = c[j] * b0 - s[j] * b1;
                v1[e1] = s[j] * b0 + c[j] * b1;
            }
        }
    }
#pragma unroll
    for (int e = 0; e < 64; ++e) {
        unsigned a = base | ((unsigned)e << 12);
        phi[a] = v0[e];
        phi[DIMN + a] = v1[e];
    }
    // measure q4..q8 (x-pairs within bits 12..17; z-mask bits >=18 via base)
    int lane = threadIdx.x & 63, w = threadIdx.x >> 6;
#pragma unroll
    for (int i = 4; i <= 8; ++i) {
        unsigned ex  = M.xm[i] >> 12;                      // 6-bit
        unsigned zme = (M.zm[i] >> 12) & 63u;
        unsigned bs31 = ((unsigned)__popc(base & M.zm[i]) & 1u) << 31;
        float t00 = 0.f, t11 = 0.f, t01 = 0.f, u01 = 0.f;
#pragma unroll
        for (int e = 0; e < 64; ++e) {
            int ep = e ^ (int)ex;
            t00 += v0[e] * v0[ep];
            t11 += v1[e] * v1[ep];
            float p = v0[e] * v1[ep];
            t01 += p;
            unsigned sg = ((unsigned)__popc((unsigned)ep & zme) & 1u) << 31;
            u01 += fflip(p, sg ^ bs31);
        }
        float vals[4] = { t00, t11, t01, u01 };
#pragma unroll
        for (int j = 0; j < 4; ++j) {
            float v = wave_sum(vals[j]);
            if (lane == 0) red[w * 20 + (i - 4) * 4 + j] = v;
        }
    }
    __syncthreads();
    int t = threadIdx.x;
    if (t < 20) {
        float r = red[t] + red[20 + t] + red[40 + t] + red[60 + t];
        atomicAdd(&acc[16 + t], r);                         // acc[16..35] = q4..q8
    }
}

// ---- RY layer 2 bits 0..11 (register-staged) + q10..q20 X/Y + ALL Z measurements ----
__global__ __launch_bounds__(256) void k_low(float* __restrict__ phi,
                                             const float* __restrict__ trig,
                                             float* __restrict__ acc) {
    constexpr MaskSet M = buildMasks();
    __shared__ float As[4096];
    __shared__ float Bs[4096];
    __shared__ float red[4 * 44];
    float4* As4 = (float4*)As;
    float4* Bs4 = (float4*)Bs;
    int t = threadIdx.x;
    unsigned base = blockIdx.x * 4096u;
    float a[16], b[16];

    // ---- phase 0: global load (16 consecutive elems/thread), gates bits 0..3 ----
    {
        const float4* g0 = (const float4*)(phi + base);
        const float4* g1 = (const float4*)(phi + DIMN + base);
#pragma unroll
        for (int k = 0; k < 4; ++k) {
            float4 va = g0[4 * t + k];
            a[4 * k] = va.x; a[4 * k + 1] = va.y; a[4 * k + 2] = va.z; a[4 * k + 3] = va.w;
            float4 vb = g1[4 * t + k];
            b[4 * k] = vb.x; b[4 * k + 1] = vb.y; b[4 * k + 2] = vb.z; b[4 * k + 3] = vb.w;
        }
#pragma unroll
        for (int g = 0; g < 4; ++g) {
            float c = trig[2 * NQ + g], s = trig[3 * NQ + g];
#pragma unroll
            for (int e = 0; e < 16; ++e) {
                if (!(e & (1 << g))) {
                    int e1 = e | (1 << g);
                    float x0 = a[e], x1 = a[e1];
                    a[e] = c * x0 - s * x1; a[e1] = s * x0 + c * x1;
                    float y0 = b[e], y1 = b[e1];
                    b[e] = c * y0 - s * y1; b[e1] = s * y0 + c * y1;
                }
            }
        }
        unsigned sw = (unsigned)(t >> 4) & 3u;
#pragma unroll
        for (int k = 0; k < 4; ++k) {
            unsigned f = ((unsigned)(4 * t + k)) ^ sw;
            As4[f] = make_float4(a[4 * k], a[4 * k + 1], a[4 * k + 2], a[4 * k + 3]);
            Bs4[f] = make_float4(b[4 * k], b[4 * k + 1], b[4 * k + 2], b[4 * k + 3]);
        }
    }
    __syncthreads();

    // ---- phase 1: exchange to bits 4..7 ownership, gates bits 4..7 ----
    {
        unsigned lo = (unsigned)t & 15u, hi = (unsigned)t >> 4;
        unsigned swz = (hi & 3u) << 2;
#pragma unroll
        for (int j = 0; j < 16; ++j) {
            unsigned i = lo | ((unsigned)j << 4) | (hi << 8);
            a[j] = As[i ^ swz];
            b[j] = Bs[i ^ swz];
        }
#pragma unroll
        for (int g = 0; g < 4; ++g) {
            float c = trig[2 * NQ + 4 + g], s = trig[3 * NQ + 4 + g];
#pragma unroll
            for (int e = 0; e < 16; ++e) {
                if (!(e & (1 << g))) {
                    int e1 = e | (1 << g);
                    float x0 = a[e], x1 = a[e1];
                    a[e] = c * x0 - s * x1; a[e1] = s * x0 + c * x1;
                    float y0 = b[e], y1 = b[e1];
                    b[e] = c * y0 - s * y1; b[e1] = s * y0 + c * y1;
                }
            }
        }
#pragma unroll
        for (int j = 0; j < 16; ++j) {
            unsigned i = lo | ((unsigned)j << 4) | (hi << 8);
            As[i ^ swz] = a[j];
            Bs[i ^ swz] = b[j];
        }
    }
    __syncthreads();

    // ---- phase 2: exchange to bits 8..11 ownership, gates bits 8..11, write out ----
    {
#pragma unroll
        for (int j = 0; j < 16; ++j) {
            unsigned i = (unsigned)t | ((unsigned)j << 8);
            unsigned p = i ^ (((unsigned)j & 3u) << 2);
            a[j] = As[p];
            b[j] = Bs[p];
        }
#pragma unroll
        for (int g = 0; g < 4; ++g) {
            float c = trig[2 * NQ + 8 + g], s = trig[3 * NQ + 8 + g];
#pragma unroll
            for (int e = 0; e < 16; ++e) {
                if (!(e & (1 << g))) {
                    int e1 = e | (1 << g);
                    float x0 = a[e], x1 = a[e1];
                    a[e] = c * x0 - s * x1; a[e1] = s * x0 + c * x1;
                    float y0 = b[e], y1 = b[e1];
                    b[e] = c * y0 - s * y1; b[e1] = s * y0 + c * y1;
                }
            }
        }
#pragma unroll
        for (int j = 0; j < 16; ++j) {
            unsigned i = (unsigned)t | ((unsigned)j << 8);
            phi[base + i] = a[j];
            phi[DIMN + base + i] = b[j];
            unsigned p = i ^ (((unsigned)j & 3u) << 2);
            As[p] = a[j];
            Bs[p] = b[j];
        }
    }

    // ---- fused Z measurement from final registers a[],b[] ----
    float SSv[3], z0v[3], z1v[3], z2v[3], d4v[3];
    {
#pragma unroll
        for (int c = 0; c < 3; ++c) {
            float p[16];
#pragma unroll
            for (int j = 0; j < 16; ++j)
                p[j] = (c == 0) ? a[j] * a[j] : (c == 1) ? b[j] * b[j] : a[j] * b[j];
            float s1[8], d1[8];
#pragma unroll
            for (int j = 0; j < 8; ++j) { s1[j] = p[j] + p[j + 8]; d1[j] = p[j] - p[j + 8]; }
            float s2[4], d2[4];
#pragma unroll
            for (int j = 0; j < 4; ++j) { s2[j] = s1[j] + s1[j + 4]; d2[j] = d1[j] - d1[j + 4]; }
            float d3a = d2[0] - d2[2], d3b = d2[1] - d2[3];
            SSv[c] = (s2[0] + s2[1]) + (s2[2] + s2[3]);
            z0v[c] = ((d1[0] + d1[1]) + (d1[2] + d1[3])) + ((d1[4] + d1[5]) + (d1[6] + d1[7]));
            z1v[c] = (d2[0] + d2[1]) + (d2[2] + d2[3]);
            z2v[c] = d3a + d3b;
            d4v[c] = d3a - d3b;
        }
    }
    {
        unsigned Wt = (unsigned)t;
        Wt ^= Wt >> 1; Wt ^= Wt >> 2; Wt ^= Wt >> 4;
        int lane = t & 63, w = t >> 6;
#pragma unroll
        for (int c = 0; c < 3; ++c) {
            float v;
            v = wave_sum(SSv[c]); if (lane == 0) red[w * 39 + c] = v;
            v = wave_sum(z0v[c]); if (lane == 0) red[w * 39 + 3 + c] = v;
            v = wave_sum(z1v[c]); if (lane == 0) red[w * 39 + 6 + c] = v;
            v = wave_sum(z2v[c]); if (lane == 0) red[w * 39 + 9 + c] = v;
            v = wave_sum(d4v[c]); if (lane == 0) red[w * 39 + 12 + c] = v;
#pragma unroll
            for (int k = 4; k < 12; ++k) {
                unsigned sb = ((Wt >> (11 - k)) & 1u) << 31;
                v = wave_sum(fflip(d4v[c], sb));
                if (lane == 0) red[w * 39 + 3 + 3 * k + c] = v;
            }
        }
    }
    __syncthreads();
    if (t < 66) {
        int c = t % 3, q = t / 3;
        int slot = (q == 0 || q == 21) ? (3 + 33 + c) : (q < 10 ? c : 3 + 3 * (q - 10) + c);
        float val = red[slot] + red[39 + slot] + red[78 + slot] + red[117 + slot];
        unsigned sg = (unsigned)__popc(base & M.zm[q]) & 1u;
        atomicAdd(&acc[4 * NQ + 3 * q + c], sg ? -val : val);
    }
    __syncthreads();

    // ---- measurements q10..q20 (masks within bits 0..11), vectorized from LDS ----
    int lane = t & 63, w = t >> 6;
#pragma unroll
    for (int i = 0; i < 11; ++i) {
        unsigned m = M.xm[10 + i], zm = M.zm[10 + i];
        unsigned zb = (unsigned)__popc(base & zm) & 1u;
        float t00 = 0.f, t11 = 0.f, t01 = 0.f, u01 = 0.f;
        if (i < 10) {
            int gb = topbit_c(M.xm[10 + i]) - 2;
            unsigned mg4 = m >> 2;
            unsigned swap2 = m & 3u;            // 0 or 2
#pragma unroll
            for (int r = 0; r < 2; ++r) {
                unsigned gc = (unsigned)t + 256u * r;
                unsigned g = ((gc >> gb) << (gb + 1)) | (gc & ((1u << gb) - 1u));
                unsigned gx = g ^ mg4;
                float4 a0 = As4[ph4(g)],  a1 = Bs4[ph4(g)];
                float4 b0 = As4[ph4(gx)], b1 = Bs4[ph4(gx)];
                if (swap2) {
                    b0 = make_float4(b0.z, b0.w, b0.x, b0.y);
                    b1 = make_float4(b1.z, b1.w, b1.x, b1.y);
                }
                unsigned szg = ((unsigned)__popc((g << 2) & zm) + zb) & 1u;
                unsigned szx = ((unsigned)__popc((gx << 2) & zm) + zb) & 1u;
                unsigned fg = szg << 31, fx = szx << 31;
                const float* A0 = &a0.x; const float* A1 = &a1.x;
                const float* B0 = &b0.x; const float* B1 = &b1.x;
#pragma unroll
                for (int j = 0; j < 4; ++j) {
                    t00 += A0[j] * B0[j];
                    t11 += A1[j] * B1[j];
                    float p = A0[j] * B1[j], r2 = B0[j] * A1[j];
                    t01 += p + r2;
                    u01 += fflip(p, fx) + fflip(r2, fg);
                }
            }
            t00 *= 2.f; t11 *= 2.f;
        } else {
            // q20: m = 3, partner within float4
#pragma unroll
            for (int k = 0; k < 4; ++k) {
                unsigned g = (unsigned)t + 256u * k;
                float4 a0 = As4[ph4(g)], a1 = Bs4[ph4(g)];
                unsigned szg = ((unsigned)__popc((g << 2) & zm) + zb) & 1u;
                const float* A0 = &a0.x; const float* A1 = &a1.x;
#pragma unroll
                for (int j = 0; j < 4; ++j) {
                    int jx = j ^ 3;
                    float p = A0[j] * A0[jx];
                    float q2 = A1[j] * A1[jx];
                    float cr = A0[j] * A1[jx];
                    t00 += p; t11 += q2; t01 += cr;
                    unsigned sj = ((unsigned)(jx >> 1) & 1u) ^ szg;   // zm&3 == 2
                    u01 += fflip(cr, sj << 31);
                }
            }
        }
        float vals[4] = { t00, t11, t01, u01 };
#pragma unroll
        for (int j = 0; j < 4; ++j) {
            float v = wave_sum(vals[j]);
            if (lane == 0) red[w * 44 + 4 * i + j] = v;
        }
    }
    __syncthreads();
    if (t < 44) {
        float r = red[t] + red[44 + t] + red[88 + t] + red[132 + t];
        atomicAdd(&acc[40 + t], r);
    }
}

// ------- slice X/Y measurements for q0, q9, q21 — grid (256, 3) -----------
struct Meas3Arg { unsigned xm[3]; unsigned zm[3]; int gbit[3]; int qn[3]; };

__global__ __launch_bounds__(256) void k_measS(const float* __restrict__ phi,
                                               float* __restrict__ acc,
                                               Meas3Arg M) {
    __shared__ float red[16];
    int t = threadIdx.x;
    int slice = blockIdx.y;
    unsigned m = M.xm[slice], zm = M.zm[slice];
    int gb = M.gbit[slice];
    unsigned mg4 = m >> 2;
    unsigned ml2 = m & 3u;                      // 0 or 1
    unsigned zl = zm & 3u;
    unsigned pg31[4], px31[4];
#pragma unroll
    for (int j = 0; j < 4; ++j) {
        pg31[j] = (((unsigned)__popc((unsigned)j & zl) & 1u) << 31);
        px31[j] = (((unsigned)__popc(((unsigned)j ^ ml2) & zl) & 1u) << 31);
    }
    unsigned tid = blockIdx.x * 256u + (unsigned)t;   // [0, 65536)
    const float4* p0 = (const float4*)phi;
    const float4* p1 = (const float4*)(phi + DIMN);
    float t00 = 0.f, t11 = 0.f, t01 = 0.f, u01 = 0.f;
#pragma unroll
    for (int it = 0; it < 8; ++it) {
        unsigned gc = tid + (unsigned)it * 65536u;    // [0, 2^19)
        unsigned g = ((gc >> gb) << (gb + 1)) | (gc & ((1u << gb) - 1u));
        unsigned gx = g ^ mg4;
        float4 a0 = p0[g], a1 = p1[g];
        float4 b0 = p0[gx], b1 = p1[gx];
        if (ml2) {
            b0 = make_float4(b0.y, b0.x, b0.w, b0.z);
            b1 = make_float4(b1.y, b1.x, b1.w, b1.z);
        }
        unsigned fg = (((unsigned)__popc((g << 2) & zm) & 1u) << 31);
        unsigned fx = (((unsigned)__popc((gx << 2) & zm) & 1u) << 31);
        const float* A0 = &a0.x; const float* A1 = &a1.x;
        const float* B0 = &b0.x; const float* B1 = &b1.x;
#pragma unroll
        for (int j = 0; j < 4; ++j) {
            t00 += A0[j] * B0[j];
            t11 += A1[j] * B1[j];
            float p = A0[j] * B1[j], r = B0[j] * A1[j];
            t01 += p + r;
            u01 += fflip(p, fx ^ px31[j]) + fflip(r, fg ^ pg31[j]);
        }
    }
    t00 *= 2.f; t11 *= 2.f;
    int lane = t & 63, w = t >> 6;
    float vals[4] = { t00, t11, t01, u01 };
#pragma unroll
    for (int j = 0; j < 4; ++j) {
        float v = wave_sum(vals[j]);
        if (lane == 0) red[w * 4 + j] = v;
    }
    __syncthreads();
    if (t < 4) {
        float r = red[t] + red[4 + t] + red[8 + t] + red[12 + t];
        atomicAdd(&acc[4 * M.qn[slice] + t], r);
    }
}

// ---------------- finalize: combine 154 sums into the scalar loss ----------------
__global__ __launch_bounds__(64) void k_final(const float* __restrict__ acc,
                                              float* __restrict__ out) {
    int t = threadIdx.x;
    float v = 0.f;
    if (t < NQ) {
        float t00 = acc[4 * t], t11 = acc[4 * t + 1];
        float t01 = acc[4 * t + 2], u01 = acc[4 * t + 3];
        float d = t00 - t11;
        v = 0.5f * d * d + 2.f * t01 * t01 + 2.f * u01 * u01;   // X op + Y op
    } else if (t < 2 * NQ) {
        int q = t - NQ;
        float z0 = acc[4 * NQ + 3 * q], z1 = acc[4 * NQ + 3 * q + 1];
        float zz = acc[4 * NQ + 3 * q + 2];
        float d = z0 - z1;
        v = 0.5f * d * d + 2.f * zz * zz;                       // Z op
    }
    v += __shfl_down(v, 32); v += __shfl_down(v, 16); v += __shfl_down(v, 8);
    v += __shfl_down(v, 4);  v += __shfl_down(v, 2);  v += __shfl_down(v, 1);
    if (t == 0) out[0] = v;
}

extern "C" void kernel_launch(void* const* d_in, const int* in_sizes, int n_in,
                              void* d_out, int out_size, void* d_ws, size_t ws_size,
                              hipStream_t stream) {
    const float* theta = (const float*)d_in[0];
    float* out  = (float*)d_out;
    float* ws   = (float*)d_ws;
    float* phi  = ws;                          // 2 * DIMN floats (32 MB)
    float* acc  = ws + 2 * (size_t)DIMN;       // 256 floats
    float* trig = acc + 256;                   // 88 floats

    constexpr MaskSet M = buildMasks();

    Meas3Arg m3;
    const int qs[3] = { 0, 9, 21 };
    for (int i = 0; i < 3; ++i) {
        int q = qs[i];
        m3.xm[i] = M.xm[q]; m3.zm[i] = M.zm[q];
        m3.gbit[i] = topbit_c(M.xm[q]) - 2;
        m3.qn[i] = q;
    }

    k_prep<<<1, 256, 0, stream>>>(theta, acc, trig);
    k_genHi<<<512, 256, 0, stream>>>(phi, trig, acc);
    k_mid<<<256, 256, 0, stream>>>(phi, trig, acc);
    k_low<<<1024, 256, 0, stream>>>(phi, trig, acc);
    k_measS<<<dim3(256, 3), 256, 0, stream>>>(phi, acc, m3);
    k_final<<<1, 64, 0, stream>>>(acc, out);
}

// Round 8
// 165.038 us; speedup vs baseline: 4.0383x; 1.0087x over previous
//
#include <hip/hip_runtime.h>

#define NQ 22
#define DIMN (1u << NQ)

// ---------------- compile-time circuit algebra (circuit is fixed) ----------------
struct MaskSet {
    unsigned L[NQ];      // CNOT-ring layer over GF(2): bit b of Lx = parity(x & L[b])
    unsigned Linv[NQ];
    unsigned xm[NQ];     // conjugated X masks
    unsigned zm[NQ];     // conjugated Z masks (suffix masks)
    unsigned frowHi[5];  // P-toggle masks for y bits 17..21 (columns of Linv)
};

constexpr MaskSet buildMasks() {
    MaskSet M{};
    for (int b = 0; b < NQ; ++b) M.L[b] = 1u << b;
    for (int q = 0; q < NQ; ++q) {
        int bc = NQ - 1 - q, bt = NQ - 1 - ((q + 1) % NQ);
        M.L[bt] ^= M.L[bc];
    }
    unsigned mat[NQ] = {}, aug[NQ] = {};
    for (int b = 0; b < NQ; ++b) { mat[b] = M.L[b]; aug[b] = 1u << b; }
    for (int col = 0; col < NQ; ++col) {
        int piv = col;
        while (!((mat[piv] >> col) & 1u)) ++piv;
        unsigned tm = mat[piv]; mat[piv] = mat[col]; mat[col] = tm;
        unsigned ta = aug[piv]; aug[piv] = aug[col]; aug[col] = ta;
        for (int r = 0; r < NQ; ++r)
            if (r != col && ((mat[r] >> col) & 1u)) { mat[r] ^= mat[col]; aug[r] ^= aug[col]; }
    }
    for (int b = 0; b < NQ; ++b) M.Linv[b] = aug[b];
    for (int j = 0; j < NQ; ++j) {
        int b = NQ - 1 - j;
        unsigned xmv = 0;
        for (int r = 0; r < NQ; ++r)
            if ((aug[r] >> b) & 1u) xmv |= 1u << r;
        M.xm[j] = xmv;       // q0..9: {21-j,20-j}; q10..20: low pairs; q21: {0,20,21}
        M.zm[j] = M.L[b];    // suffix masks
    }
    for (int j = 0; j < 5; ++j) {
        unsigned f = 0;
        for (int r = 0; r < NQ; ++r)
            if ((aug[r] >> (17 + j)) & 1u) f |= 1u << r;
        M.frowHi[j] = f;
    }
    return M;
}
constexpr int topbit_c(unsigned v) { int b = 0; while (v >> (b + 1)) ++b; return b; }
constexpr unsigned unionHi() {
    MaskSet M = buildMasks();
    unsigned u = 0;
    for (int j = 0; j < 5; ++j) u |= M.frowHi[j];
    return u;
}
static_assert((unionHi() & 0xFFFFu) == 0, "frowHi must only touch bits 16..21");

__device__ __forceinline__ float wave_sum(float v) {
    v += __shfl_down(v, 32); v += __shfl_down(v, 16); v += __shfl_down(v, 8);
    v += __shfl_down(v, 4);  v += __shfl_down(v, 2);  v += __shfl_down(v, 1);
    return v;
}
__device__ __forceinline__ float fflip(float v, unsigned sbit31) {
    return __int_as_float(__float_as_int(v) ^ (int)sbit31);
}
__device__ __forceinline__ unsigned ph4(unsigned g) { return g ^ ((g >> 6) & 3u); }

// ---------------- prep: zero accumulators, compute cos/sin tables ----------------
__global__ __launch_bounds__(256) void k_prep(const float* __restrict__ theta,
                                              float* __restrict__ acc,
                                              float* __restrict__ trig) {
    int t = threadIdx.x;
    acc[t] = 0.f;
    if (t < 2 * NQ) {
        int l = t / NQ, q = t % NQ, b = NQ - 1 - q;
        float h = 0.5f * theta[t];
        trig[l * 2 * NQ + b]      = cosf(h);
        trig[l * 2 * NQ + NQ + b] = sinf(h);
    }
}

// ---- generator in e=bits17..21 tile + gates 17..21 + measure q1,q2,q3 ----
__global__ __launch_bounds__(256, 1) void k_genHi(float* __restrict__ phi,
                                                  const float* __restrict__ trig,
                                                  float* __restrict__ acc) {
    constexpr MaskSet M = buildMasks();
    __shared__ float red[4 * 12];
    unsigned base = blockIdx.x * 256u + threadIdx.x;       // y bits 0..16
    unsigned P0 = 0;
#pragma unroll
    for (int b = 0; b < NQ; ++b)
        P0 |= ((unsigned)__popc(base & M.Linv[b]) & 1u) << b;
    // common product over bits 1..15 (consumed immediately, not kept)
    float pc = 1.f;
#pragma unroll
    for (int b = 1; b < 16; ++b) {
        float cvb = trig[b], svb = trig[NQ + b];
        pc *= ((P0 >> b) & 1u) ? svb : cvb;
    }
    float cv0 = trig[0], sv0 = trig[NQ];
    float C0 = pc * ((P0 & 1u) ? sv0 : cv0);
    float C1 = pc * ((P0 & 1u) ? cv0 : -sv0);
    // variable part: bits 16..21
    float cb[6], sb[6];
#pragma unroll
    for (int k = 0; k < 6; ++k) { cb[k] = trig[16 + k]; sb[k] = trig[NQ + 16 + k]; }
    unsigned u0 = P0 >> 16;                                // 6 bits
    float v0[32], v1[32];
#pragma unroll
    for (int e = 0; e < 32; ++e) {
        unsigned F = 0;
        if (e & 1)  F ^= M.frowHi[0];
        if (e & 2)  F ^= M.frowHi[1];
        if (e & 4)  F ^= M.frowHi[2];
        if (e & 8)  F ^= M.frowHi[3];
        if (e & 16) F ^= M.frowHi[4];
        unsigned u = u0 ^ (F >> 16);
        float vp = (u & 1u) ? sb[0] : cb[0];
#pragma unroll
        for (int k = 1; k < 6; ++k) vp *= ((u >> k) & 1u) ? sb[k] : cb[k];
        v0[e] = vp * C0;
        v1[e] = vp * C1;
    }
    float c2[5], s2[5];
#pragma unroll
    for (int j = 0; j < 5; ++j) {
        c2[j] = trig[2 * NQ + 17 + j];
        s2[j] = trig[3 * NQ + 17 + j];
    }
#pragma unroll
    for (int j = 0; j < 5; ++j) {
#pragma unroll
        for (int e = 0; e < 32; ++e) {
            if (!(e & (1 << j))) {
                int e1 = e | (1 << j);
                float a0 = v0[e], a1 = v0[e1];
                v0[e]  = c2[j] * a0 - s2[j] * a1;
                v0[e1] = s2[j] * a0 + c2[j] * a1;
                float b0 = v1[e], b1 = v1[e1];
                v1[e]  = c2[j] * b0 - s2[j] * b1;
                v1[e1] = s2[j] * b0 + c2[j] * b1;
            }
        }
    }
#pragma unroll
    for (int e = 0; e < 32; ++e) {
        unsigned a = base | ((unsigned)e << 17);
        phi[a] = v0[e];
        phi[DIMN + a] = v1[e];
    }
    // measure q1..q3 (x-pairs and z-masks entirely within bits 17..21)
    int lane = threadIdx.x & 63, w = threadIdx.x >> 6;
#pragma unroll
    for (int i = 1; i <= 3; ++i) {
        unsigned ex  = M.xm[i] >> 17;
        unsigned zme = M.zm[i] >> 17;
        float t00 = 0.f, t11 = 0.f, t01 = 0.f, u01 = 0.f;
#pragma unroll
        for (int e = 0; e < 32; ++e) {
            int ep = e ^ (int)ex;
            t00 += v0[e] * v0[ep];
            t11 += v1[e] * v1[ep];
            float p = v0[e] * v1[ep];
            t01 += p;
            unsigned sg = ((unsigned)__popc((unsigned)ep & zme) & 1u) << 31;
            u01 += fflip(p, sg);
        }
        float vals[4] = { t00, t11, t01, u01 };
#pragma unroll
        for (int j = 0; j < 4; ++j) {
            float v = wave_sum(vals[j]);
            if (lane == 0) red[w * 12 + (i - 1) * 4 + j] = v;
        }
    }
    __syncthreads();
    int t = threadIdx.x;
    if (t < 12) {
        float r = red[t] + red[12 + t] + red[24 + t] + red[36 + t];
        atomicAdd(&acc[4 + t], r);                          // acc[4..15] = q1..q3
    }
}

// ---- e=bits12..16 tile: gates 12..16 + measure q5..q8 (32-elem tile, 8 waves/CU) ----
__global__ __launch_bounds__(256, 1) void k_midA(float* __restrict__ phi,
                                                 const float* __restrict__ trig,
                                                 float* __restrict__ acc) {
    constexpr MaskSet M = buildMasks();
    __shared__ float red[4 * 16];
    unsigned tid = blockIdx.x * 256u + threadIdx.x;        // [0, 2^17)
    unsigned base = (tid & 0xFFFu) | ((tid >> 12) << 17);  // bits 0..11 + 17..21
    float v0[32], v1[32];
#pragma unroll
    for (int e = 0; e < 32; ++e) {
        unsigned a = base | ((unsigned)e << 12);
        v0[e] = phi[a];
        v1[e] = phi[DIMN + a];
    }
    float c[5], s[5];
#pragma unroll
    for (int j = 0; j < 5; ++j) {
        c[j] = trig[2 * NQ + 12 + j];
        s[j] = trig[3 * NQ + 12 + j];
    }
#pragma unroll
    for (int j = 0; j < 5; ++j) {
#pragma unroll
        for (int e = 0; e < 32; ++e) {
            if (!(e & (1 << j))) {
                int e1 = e | (1 << j);
                float a0 = v0[e], a1 = v0[e1];
                v0[e]  = c[j] * a0 - s[j] * a1;
                v0[e1] = s[j] * a0 + c[j] * a1;
                float b0 = v1[e], b1 = v1[e1];
                v1[e]  = c[j] * b0 - s[j] * b1;
                v1[e1] = s[j] * b0 + c[j] * b1;
            }
        }
    }
#pragma unroll
    for (int e = 0; e < 32; ++e) {
        unsigned a = base | ((unsigned)e << 12);
        phi[a] = v0[e];
        phi[DIMN + a] = v1[e];
    }
    // measure q5..q8 (x-pairs within bits 12..16; z-masks suffix >= 13)
    int lane = threadIdx.x & 63, w = threadIdx.x >> 6;
#pragma unroll
    for (int i = 5; i <= 8; ++i) {
        unsigned ex  = (M.xm[i] >> 12) & 31u;
        unsigned zme = (M.zm[i] >> 12) & 31u;
        unsigned bs31 = ((unsigned)__popc(base & M.zm[i]) & 1u) << 31;
        float t00 = 0.f, t11 = 0.f, t01 = 0.f, u01 = 0.f;
#pragma unroll
        for (int e = 0; e < 32; ++e) {
            int ep = e ^ (int)ex;
            t00 += v0[e] * v0[ep];
            t11 += v1[e] * v1[ep];
            float p = v0[e] * v1[ep];
            t01 += p;
            unsigned sg = ((unsigned)__popc((unsigned)ep & zme) & 1u) << 31;
            u01 += fflip(p, sg ^ bs31);
        }
        float vals[4] = { t00, t11, t01, u01 };
#pragma unroll
        for (int j = 0; j < 4; ++j) {
            float v = wave_sum(vals[j]);
            if (lane == 0) red[w * 16 + (i - 5) * 4 + j] = v;
        }
    }
    __syncthreads();
    int t = threadIdx.x;
    if (t < 16) {
        float r = red[t] + red[16 + t] + red[32 + t] + red[48 + t];
        atomicAdd(&acc[20 + t], r);                         // acc[20..35] = q5..q8
    }
}

// ---- RY layer 2 bits 0..11 + q10..q20 X/Y + ALL Z measurements ----
__global__ __launch_bounds__(256) void k_low(float* __restrict__ phi,
                                             const float* __restrict__ trig,
                                             float* __restrict__ acc) {
    constexpr MaskSet M = buildMasks();
    __shared__ float As[4096];
    __shared__ float Bs[4096];
    __shared__ float red[4 * 44];
    float4* As4 = (float4*)As;
    float4* Bs4 = (float4*)Bs;
    int t = threadIdx.x;
    unsigned base = blockIdx.x * 4096u;
    float a[16], b[16];

    // ---- phase 0: global load (16 consecutive elems/thread), gates bits 0..3 ----
    {
        const float4* g0 = (const float4*)(phi + base);
        const float4* g1 = (const float4*)(phi + DIMN + base);
#pragma unroll
        for (int k = 0; k < 4; ++k) {
            float4 va = g0[4 * t + k];
            a[4 * k] = va.x; a[4 * k + 1] = va.y; a[4 * k + 2] = va.z; a[4 * k + 3] = va.w;
            float4 vb = g1[4 * t + k];
            b[4 * k] = vb.x; b[4 * k + 1] = vb.y; b[4 * k + 2] = vb.z; b[4 * k + 3] = vb.w;
        }
#pragma unroll
        for (int g = 0; g < 4; ++g) {
            float c = trig[2 * NQ + g], s = trig[3 * NQ + g];
#pragma unroll
            for (int e = 0; e < 16; ++e) {
                if (!(e & (1 << g))) {
                    int e1 = e | (1 << g);
                    float x0 = a[e], x1 = a[e1];
                    a[e] = c * x0 - s * x1; a[e1] = s * x0 + c * x1;
                    float y0 = b[e], y1 = b[e1];
                    b[e] = c * y0 - s * y1; b[e1] = s * y0 + c * y1;
                }
            }
        }
        unsigned sw = (unsigned)(t >> 4) & 3u;
#pragma unroll
        for (int k = 0; k < 4; ++k) {
            unsigned f = ((unsigned)(4 * t + k)) ^ sw;
            As4[f] = make_float4(a[4 * k], a[4 * k + 1], a[4 * k + 2], a[4 * k + 3]);
            Bs4[f] = make_float4(b[4 * k], b[4 * k + 1], b[4 * k + 2], b[4 * k + 3]);
        }
    }
    __syncthreads();

    // ---- phase 1: exchange to bits 4..7 ownership, gates bits 4..7 ----
    {
        unsigned lo = (unsigned)t & 15u, hi = (unsigned)t >> 4;
        unsigned swz = (hi & 3u) << 2;
#pragma unroll
        for (int j = 0; j < 16; ++j) {
            unsigned i = lo | ((unsigned)j << 4) | (hi << 8);
            a[j] = As[i ^ swz];
            b[j] = Bs[i ^ swz];
        }
#pragma unroll
        for (int g = 0; g < 4; ++g) {
            float c = trig[2 * NQ + 4 + g], s = trig[3 * NQ + 4 + g];
#pragma unroll
            for (int e = 0; e < 16; ++e) {
                if (!(e & (1 << g))) {
                    int e1 = e | (1 << g);
                    float x0 = a[e], x1 = a[e1];
                    a[e] = c * x0 - s * x1; a[e1] = s * x0 + c * x1;
                    float y0 = b[e], y1 = b[e1];
                    b[e] = c * y0 - s * y1; b[e1] = s * y0 + c * y1;
                }
            }
        }
#pragma unroll
        for (int j = 0; j < 16; ++j) {
            unsigned i = lo | ((unsigned)j << 4) | (hi << 8);
            As[i ^ swz] = a[j];
            Bs[i ^ swz] = b[j];
        }
    }
    __syncthreads();

    // ---- phase 2: exchange to bits 8..11 ownership, gates bits 8..11, write out ----
    {
#pragma unroll
        for (int j = 0; j < 16; ++j) {
            unsigned i = (unsigned)t | ((unsigned)j << 8);
            unsigned p = i ^ (((unsigned)j & 3u) << 2);
            a[j] = As[p];
            b[j] = Bs[p];
        }
#pragma unroll
        for (int g = 0; g < 4; ++g) {
            float c = trig[2 * NQ + 8 + g], s = trig[3 * NQ + 8 + g];
#pragma unroll
            for (int e = 0; e < 16; ++e) {
                if (!(e & (1 << g))) {
                    int e1 = e | (1 << g);
                    float x0 = a[e], x1 = a[e1];
                    a[e] = c * x0 - s * x1; a[e1] = s * x0 + c * x1;
                    float y0 = b[e], y1 = b[e1];
                    b[e] = c * y0 - s * y1; b[e1] = s * y0 + c * y1;
                }
            }
        }
#pragma unroll
        for (int j = 0; j < 16; ++j) {
            unsigned i = (unsigned)t | ((unsigned)j << 8);
            phi[base + i] = a[j];
            phi[DIMN + base + i] = b[j];
            unsigned p = i ^ (((unsigned)j & 3u) << 2);
            As[p] = a[j];
            Bs[p] = b[j];
        }
    }

    // ---- fused Z measurement from final registers a[],b[] ----
    float SSv[3], z0v[3], z1v[3], z2v[3], d4v[3];
    {
#pragma unroll
        for (int c = 0; c < 3; ++c) {
            float p[16];
#pragma unroll
            for (int j = 0; j < 16; ++j)
                p[j] = (c == 0) ? a[j] * a[j] : (c == 1) ? b[j] * b[j] : a[j] * b[j];
            float s1[8], d1[8];
#pragma unroll
            for (int j = 0; j < 8; ++j) { s1[j] = p[j] + p[j + 8]; d1[j] = p[j] - p[j + 8]; }
            float s2[4], d2[4];
#pragma unroll
            for (int j = 0; j < 4; ++j) { s2[j] = s1[j] + s1[j + 4]; d2[j] = d1[j] - d1[j + 4]; }
            float d3a = d2[0] - d2[2], d3b = d2[1] - d2[3];
            SSv[c] = (s2[0] + s2[1]) + (s2[2] + s2[3]);
            z0v[c] = ((d1[0] + d1[1]) + (d1[2] + d1[3])) + ((d1[4] + d1[5]) + (d1[6] + d1[7]));
            z1v[c] = (d2[0] + d2[1]) + (d2[2] + d2[3]);
            z2v[c] = d3a + d3b;
            d4v[c] = d3a - d3b;
        }
    }
    {
        unsigned Wt = (unsigned)t;
        Wt ^= Wt >> 1; Wt ^= Wt >> 2; Wt ^= Wt >> 4;
        int lane = t & 63, w = t >> 6;
#pragma unroll
        for (int c = 0; c < 3; ++c) {
            float v;
            v = wave_sum(SSv[c]); if (lane == 0) red[w * 39 + c] = v;
            v = wave_sum(z0v[c]); if (lane == 0) red[w * 39 + 3 + c] = v;
            v = wave_sum(z1v[c]); if (lane == 0) red[w * 39 + 6 + c] = v;
            v = wave_sum(z2v[c]); if (lane == 0) red[w * 39 + 9 + c] = v;
            v = wave_sum(d4v[c]); if (lane == 0) red[w * 39 + 12 + c] = v;
#pragma unroll
            for (int k = 4; k < 12; ++k) {
                unsigned sb = ((Wt >> (11 - k)) & 1u) << 31;
                v = wave_sum(fflip(d4v[c], sb));
                if (lane == 0) red[w * 39 + 3 + 3 * k + c] = v;
            }
        }
    }
    __syncthreads();
    if (t < 66) {
        int c = t % 3, q = t / 3;
        int slot = (q == 0 || q == 21) ? (3 + 33 + c) : (q < 10 ? c : 3 + 3 * (q - 10) + c);
        float val = red[slot] + red[39 + slot] + red[78 + slot] + red[117 + slot];
        unsigned sg = (unsigned)__popc(base & M.zm[q]) & 1u;
        atomicAdd(&acc[4 * NQ + 3 * q + c], sg ? -val : val);
    }
    __syncthreads();

    int lane = t & 63, w = t >> 6;

    // ---- q10..q12 measured from registers (x-pairs within bits 8..11 = j bits) ----
#pragma unroll
    for (int i = 0; i < 3; ++i) {
        constexpr int qn0 = 10;
        unsigned je  = (M.xm[qn0 + i] >> 8) & 15u;
        unsigned zmj = (M.zm[qn0 + i] >> 8) & 15u;
        unsigned zb31 = ((unsigned)__popc(base & M.zm[qn0 + i]) & 1u) << 31;
        float t00 = 0.f, t11 = 0.f, t01 = 0.f, u01 = 0.f;
#pragma unroll
        for (int j = 0; j < 16; ++j) {
            int jp = j ^ (int)je;
            t00 += a[j] * a[jp];
            t11 += b[j] * b[jp];
            float p = a[j] * b[jp];
            t01 += p;
            unsigned sg = ((unsigned)__popc((unsigned)jp & zmj) & 1u) << 31;
            u01 += fflip(p, sg ^ zb31);
        }
        float vals[4] = { t00, t11, t01, u01 };
#pragma unroll
        for (int j = 0; j < 4; ++j) {
            float v = wave_sum(vals[j]);
            if (lane == 0) red[w * 44 + 4 * i + j] = v;
        }
    }

    // ---- q13..q20 (masks within bits 0..8), vectorized from LDS ----
#pragma unroll
    for (int i = 3; i < 11; ++i) {
        unsigned m = M.xm[10 + i], zm = M.zm[10 + i];
        unsigned zb = (unsigned)__popc(base & zm) & 1u;
        float t00 = 0.f, t11 = 0.f, t01 = 0.f, u01 = 0.f;
        if (i < 10) {
            int gb = topbit_c(M.xm[10 + i]) - 2;
            unsigned mg4 = m >> 2;
            unsigned swap2 = m & 3u;            // 0 or 2
#pragma unroll
            for (int r = 0; r < 2; ++r) {
                unsigned gc = (unsigned)t + 256u * r;
                unsigned g = ((gc >> gb) << (gb + 1)) | (gc & ((1u << gb) - 1u));
                unsigned gx = g ^ mg4;
                float4 a0 = As4[ph4(g)],  a1 = Bs4[ph4(g)];
                float4 b0 = As4[ph4(gx)], b1 = Bs4[ph4(gx)];
                if (swap2) {
                    b0 = make_float4(b0.z, b0.w, b0.x, b0.y);
                    b1 = make_float4(b1.z, b1.w, b1.x, b1.y);
                }
                unsigned szg = ((unsigned)__popc((g << 2) & zm) + zb) & 1u;
                unsigned szx = ((unsigned)__popc((gx << 2) & zm) + zb) & 1u;
                unsigned fg = szg << 31, fx = szx << 31;
                const float* A0 = &a0.x; const float* A1 = &a1.x;
                const float* B0 = &b0.x; const float* B1 = &b1.x;
#pragma unroll
                for (int j = 0; j < 4; ++j) {
                    t00 += A0[j] * B0[j];
                    t11 += A1[j] * B1[j];
                    float p = A0[j] * B1[j], r2 = B0[j] * A1[j];
                    t01 += p + r2;
                    u01 += fflip(p, fx) + fflip(r2, fg);
                }
            }
            t00 *= 2.f; t11 *= 2.f;
        } else {
            // q20: m = 3, partner within float4
#pragma unroll
            for (int k = 0; k < 4; ++k) {
                unsigned g = (unsigned)t + 256u * k;
                float4 a0 = As4[ph4(g)], a1 = Bs4[ph4(g)];
                unsigned szg = ((unsigned)__popc((g << 2) & zm) + zb) & 1u;
                const float* A0 = &a0.x; const float* A1 = &a1.x;
#pragma unroll
                for (int j = 0; j < 4; ++j) {
                    int jx = j ^ 3;
                    float p = A0[j] * A0[jx];
                    float q2 = A1[j] * A1[jx];
                    float cr = A0[j] * A1[jx];
                    t00 += p; t11 += q2; t01 += cr;
                    unsigned sj = ((unsigned)(jx >> 1) & 1u) ^ szg;   // zm&3 == 2
                    u01 += fflip(cr, sj << 31);
                }
            }
        }
        float vals[4] = { t00, t11, t01, u01 };
#pragma unroll
        for (int j = 0; j < 4; ++j) {
            float v = wave_sum(vals[j]);
            if (lane == 0) red[w * 44 + 4 * i + j] = v;
        }
    }
    __syncthreads();
    if (t < 44) {
        float r = red[t] + red[44 + t] + red[88 + t] + red[132 + t];
        atomicAdd(&acc[40 + t], r);
    }
}

// ------- slice X/Y measurements for q0, q4, q9, q21 — grid (256, 4) -----------
struct Meas4Arg { unsigned xm[4]; unsigned zm[4]; int gbit[4]; int qn[4]; };

__global__ __launch_bounds__(256) void k_measS(const float* __restrict__ phi,
                                               float* __restrict__ acc,
                                               Meas4Arg M) {
    __shared__ float red[16];
    int t = threadIdx.x;
    int slice = blockIdx.y;
    unsigned m = M.xm[slice], zm = M.zm[slice];
    int gb = M.gbit[slice];
    unsigned mg4 = m >> 2;
    unsigned ml2 = m & 3u;                      // 0 or 1
    unsigned zl = zm & 3u;
    unsigned pg31[4], px31[4];
#pragma unroll
    for (int j = 0; j < 4; ++j) {
        pg31[j] = (((unsigned)__popc((unsigned)j & zl) & 1u) << 31);
        px31[j] = (((unsigned)__popc(((unsigned)j ^ ml2) & zl) & 1u) << 31);
    }
    unsigned tid = blockIdx.x * 256u + (unsigned)t;   // [0, 65536)
    const float4* p0 = (const float4*)phi;
    const float4* p1 = (const float4*)(phi + DIMN);
    float t00 = 0.f, t11 = 0.f, t01 = 0.f, u01 = 0.f;
#pragma unroll
    for (int it = 0; it < 8; ++it) {
        unsigned gc = tid + (unsigned)it * 65536u;    // [0, 2^19)
        unsigned g = ((gc >> gb) << (gb + 1)) | (gc & ((1u << gb) - 1u));
        unsigned gx = g ^ mg4;
        float4 a0 = p0[g], a1 = p1[g];
        float4 b0 = p0[gx], b1 = p1[gx];
        if (ml2) {
            b0 = make_float4(b0.y, b0.x, b0.w, b0.z);
            b1 = make_float4(b1.y, b1.x, b1.w, b1.z);
        }
        unsigned fg = (((unsigned)__popc((g << 2) & zm) & 1u) << 31);
        unsigned fx = (((unsigned)__popc((gx << 2) & zm) & 1u) << 31);
        const float* A0 = &a0.x; const float* A1 = &a1.x;
        const float* B0 = &b0.x; const float* B1 = &b1.x;
#pragma unroll
        for (int j = 0; j < 4; ++j) {
            t00 += A0[j] * B0[j];
            t11 += A1[j] * B1[j];
            float p = A0[j] * B1[j], r = B0[j] * A1[j];
            t01 += p + r;
            u01 += fflip(p, fx ^ px31[j]) + fflip(r, fg ^ pg31[j]);
        }
    }
    t00 *= 2.f; t11 *= 2.f;
    int lane = t & 63, w = t >> 6;
    float vals[4] = { t00, t11, t01, u01 };
#pragma unroll
    for (int j = 0; j < 4; ++j) {
        float v = wave_sum(vals[j]);
        if (lane == 0) red[w * 4 + j] = v;
    }
    __syncthreads();
    if (t < 4) {
        float r = red[t] + red[4 + t] + red[8 + t] + red[12 + t];
        atomicAdd(&acc[4 * M.qn[slice] + t], r);
    }
}

// ---------------- finalize: combine 154 sums into the scalar loss ----------------
__global__ __launch_bounds__(64) void k_final(const float* __restrict__ acc,
                                              float* __restrict__ out) {
    int t = threadIdx.x;
    float v = 0.f;
    if (t < NQ) {
        float t00 = acc[4 * t], t11 = acc[4 * t + 1];
        float t01 = acc[4 * t + 2], u01 = acc[4 * t + 3];
        float d = t00 - t11;
        v = 0.5f * d * d + 2.f * t01 * t01 + 2.f * u01 * u01;   // X op + Y op
    } else if (t < 2 * NQ) {
        int q = t - NQ;
        float z0 = acc[4 * NQ + 3 * q], z1 = acc[4 * NQ + 3 * q + 1];
        float zz = acc[4 * NQ + 3 * q + 2];
        float d = z0 - z1;
        v = 0.5f * d * d + 2.f * zz * zz;                       // Z op
    }
    v += __shfl_down(v, 32); v += __shfl_down(v, 16); v += __shfl_down(v, 8);
    v += __shfl_down(v, 4);  v += __shfl_down(v, 2);  v += __shfl_down(v, 1);
    if (t == 0) out[0] = v;
}

extern "C" void kernel_launch(void* const* d_in, const int* in_sizes, int n_in,
                              void* d_out, int out_size, void* d_ws, size_t ws_size,
                              hipStream_t stream) {
    const float* theta = (const float*)d_in[0];
    float* out  = (float*)d_out;
    float* ws   = (float*)d_ws;
    float* phi  = ws;                          // 2 * DIMN floats (32 MB)
    float* acc  = ws + 2 * (size_t)DIMN;       // 256 floats
    float* trig = acc + 256;                   // 88 floats

    constexpr MaskSet M = buildMasks();

    Meas4Arg m4;
    const int qs[4] = { 0, 4, 9, 21 };
    for (int i = 0; i < 4; ++i) {
        int q = qs[i];
        m4.xm[i] = M.xm[q]; m4.zm[i] = M.zm[q];
        m4.gbit[i] = topbit_c(M.xm[q]) - 2;
        m4.qn[i] = q;
    }

    k_prep<<<1, 256, 0, stream>>>(theta, acc, trig);
    k_genHi<<<512, 256, 0, stream>>>(phi, trig, acc);
    k_midA<<<512, 256, 0, stream>>>(phi, trig, acc);
    k_low<<<1024, 256, 0, stream>>>(phi, trig, acc);
    k_measS<<<dim3(256, 4), 256, 0, stream>>>(phi, acc, m4);
    k_final<<<1, 64, 0, stream>>>(acc, out);
}